// Round 9
// baseline (288.828 us; speedup 1.0000x reference)
//
#include <hip/hip_runtime.h>
#include <hip/hip_bf16.h>

// B=512, A=4, D=6, N=1365, E=128. Level starts {0,1,5,21,85,341}.
// One block per batch tree, 512 thr (8 waves), TARGET 2 blocks/CU (LDS 78 KB).
// Staging via __builtin_amdgcn_global_load_lds (fp32 emb rows DMA'd straight
// to LDS; no staging VGPRs, no scratch spill). A-fragments read fp32 from LDS
// and packed to bf16 at use (__float22bfloat162_rn). Wc AND Ws fragments
// VGPR-resident (demand ~115 < 128 cap). 24 phases; 2 barriers each
// (writers-done | DMA-drain); cross-block overlap replaces the software
// pipeline. Pure function of d_in: no workspace, no atomics, no memset.
#define NTOK 1365
#define ED   128
#define STR  136    // bf16 CS row stride (ushorts): 272 B
#define PRB  1056   // fp32 staging pair stride in BYTES: 2 rows*512 + 32 pad

typedef __attribute__((ext_vector_type(8))) short short8;
typedef __attribute__((ext_vector_type(4))) float f32x4;

#define MFMA(a,b,c) __builtin_amdgcn_mfma_f32_16x16x32_bf16((a),(b),(c),0,0,0)

__device__ __forceinline__ ushort f2bf(float f) {  // round-to-nearest-even
  union { float f; unsigned u; } v; v.f = f;
  unsigned r = v.u + 0x7fffu + ((v.u >> 16) & 1u);
  return (ushort)(r >> 16);
}
__device__ __forceinline__ short8 pack8(float4 a, float4 b) {
  union { __hip_bfloat162 h[4]; short8 s; } t;
  t.h[0] = __float22bfloat162_rn(float2{a.x, a.y});
  t.h[1] = __float22bfloat162_rn(float2{a.z, a.w});
  t.h[2] = __float22bfloat162_rn(float2{b.x, b.y});
  t.h[3] = __float22bfloat162_rn(float2{b.z, b.w});
  return t.s;
}

typedef __attribute__((address_space(3))) unsigned       lds_u32;
typedef __attribute__((address_space(1))) const unsigned gbl_u32;
__device__ __forceinline__ void load_lds16(const void* g, void* l) {
  // 16 B per lane; LDS dest = l + lane*16 (wave-uniform base, m97/m104)
  __builtin_amdgcn_global_load_lds((gbl_u32*)g, (lds_u32*)l, 16, 0, 0);
}

// LDS map (bytes): Xf 32*PRB = 33792 | CS4 64*272 | CS3 64*272 | CS2 16*272
// | CS1 4*272 | PM 1024 floats. Total 78144 B -> 2 blocks/CU (156.3/160 KB).
#define XF_BYTES  (32 * PRB)
#define SM_BYTES  (XF_BYTES + (64 + 64 + 16 + 4) * STR * 2 + 4096)

__global__ __launch_bounds__(512) void tree_kernel(
    const int* __restrict__ tokens, const float* __restrict__ emb,
    const float* __restrict__ WcW,  const float* __restrict__ Wcb,
    const float* __restrict__ WsW,  const float* __restrict__ Wsb,
    float* __restrict__ out) {
  extern __shared__ char smem[];
  char*   Xf  = smem;                         // fp32 staging, 64 rows pair-padded
  ushort* CS4 = (ushort*)(smem + XF_BYTES);   // leaf child-sums (per quarter)
  ushort* CS3 = CS4 + 64*STR;                 // 64 rows (= L3 node idx)
  ushort* CS2 = CS3 + 64*STR;                 // 16 rows; row 0 reused as H1
  ushort* CS1 = CS2 + 16*STR;                 // 4 rows
  float*  PM  = (float*)(CS1 + 4*STR);        // [8][128] per-wave col maxima

  const int  tid = threadIdx.x;
  const int  b   = blockIdx.x;
  const long tokbase = (long)b * NTOK;
  const int  w    = tid >> 6;                 // wave 0..7
  const int  lane = tid & 63;
  const int  n16  = lane & 15;
  const int  quad = lane >> 4;
  const int  mtg  = w >> 2, ntg = w & 3;      // 2x4 wave grid for M=64 phases
  const int  kof  = quad * 8;                 // k offset (elements)

  // ---- biases in registers (all phases share the column mapping) ----
  float bcv[2], bsv[2];
  #pragma unroll
  for (int j = 0; j < 2; j++) {
    const int c = ntg*32 + j*16 + n16;
    bcv[j] = Wcb[c]; bsv[j] = 4.f * Wsb[c];
  }

  // ---- Wc and Ws fragments VGPR-resident (64 regs total) ----
  short8 Bc[2][4], Bs[2][4];
  #pragma unroll
  for (int jt = 0; jt < 2; jt++)
    #pragma unroll
    for (int kb = 0; kb < 4; kb++) {
      const float* pc = WcW + (ntg*32 + jt*16 + n16)*ED + kb*32 + kof;
      Bc[jt][kb] = pack8(((const float4*)pc)[0], ((const float4*)pc)[1]);
      const float* ps = WsW + (ntg*32 + jt*16 + n16)*ED + kb*32 + kof;
      Bs[jt][kb] = pack8(((const float4*)ps)[0], ((const float4*)ps)[1]);
    }

  for (int i = tid; i < 1024; i += 512) PM[i] = 0.f;

  float pm[2] = {0.f, 0.f};                   // relu floor, cols ntg*32+j*16+n16

  // ---- DMA gathers: fp32 emb rows straight into Xf ----
  auto dma64 = [&](int ofs) {                 // 64 rows; 4 insts/wave, 2 rows each
    const int half  = lane >> 5;              // 0/1 -> row parity
    const int chunk = lane & 31;              // 16-B chunk within row
    #pragma unroll
    for (int t = 0; t < 4; t++) {
      const int r = w*8 + 2*t + half;
      const int tok = tokens[tokbase + ofs + r];
      const float* g = emb + (long)tok*ED + chunk*4;
      load_lds16(g, Xf + (w*4 + t)*PRB);      // lane*16 spans the 1024-B pair
    }
  };
  auto dmaS = [&](int ofs) {                  // 16 rows (extra rows junk, clamped)
    const int r = w*2 + (lane >> 5);
    const int tok = tokens[tokbase + ofs + r];
    const float* g = emb + (long)tok*ED + (lane & 31)*4;
    load_lds16(g, Xf + w*PRB);
  };

  // ---- A-fragment: fp32 LDS row -> bf16 short8 at use ----
  auto afrag = [&](int r, int kb) -> short8 {
    const char* p = Xf + (r >> 1)*PRB + (r & 1)*512 + kb*128 + quad*32;
    return pack8(((const float4*)p)[0], ((const float4*)p)[1]);
  };

  // ---- M=64 phase: acc = Xf@Wc^T (+ csrc@Ws^T); relu-max + child-quad-sums ----
  auto phase64 = [&](const ushort* csrc, ushort* csdst, int csrow0) {
    f32x4 acc[2][2];
    #pragma unroll
    for (int i = 0; i < 2; i++)
      #pragma unroll
      for (int j = 0; j < 2; j++) acc[i][j] = (f32x4){0.f,0.f,0.f,0.f};
    #pragma unroll
    for (int kb = 0; kb < 4; kb++) {
      short8 a0 = afrag(mtg*32      + n16, kb);
      short8 a1 = afrag(mtg*32 + 16 + n16, kb);
      acc[0][0]=MFMA(a0,Bc[0][kb],acc[0][0]); acc[0][1]=MFMA(a0,Bc[1][kb],acc[0][1]);
      acc[1][0]=MFMA(a1,Bc[0][kb],acc[1][0]); acc[1][1]=MFMA(a1,Bc[1][kb],acc[1][1]);
      if (csrc) {
        const int ko = kb*32 + kof;
        short8 c0 = *(const short8*)(csrc + (mtg*32      + n16)*STR + ko);
        short8 c1 = *(const short8*)(csrc + (mtg*32 + 16 + n16)*STR + ko);
        acc[0][0]=MFMA(c0,Bs[0][kb],acc[0][0]); acc[0][1]=MFMA(c0,Bs[1][kb],acc[0][1]);
        acc[1][0]=MFMA(c1,Bs[0][kb],acc[1][0]); acc[1][1]=MFMA(c1,Bs[1][kb],acc[1][1]);
      }
    }
    #pragma unroll
    for (int i = 0; i < 2; i++) {
      const int p = mtg*8 + i*4 + quad;       // C row / 4 = parent idx
      #pragma unroll
      for (int j = 0; j < 2; j++) {
        const float bb = csrc ? (bcv[j] + bsv[j]) : bcv[j];
        f32x4 A = acc[i][j];
        float h0=A[0]+bb, h1=A[1]+bb, h2=A[2]+bb, h3=A[3]+bb;
        pm[j] = fmaxf(pm[j], fmaxf(fmaxf(h0,h1), fmaxf(h2,h3)));
        csdst[(csrow0 + p)*STR + ntg*32 + j*16 + n16] =
            f2bf(A[0]+A[1]+A[2]+A[3] + 4.f*bb);
      }
    }
  };

  // ---- small phases (mtg==0 waves), reuse Bc/Bs/bcv/bsv/pm ----
  auto smallphase = [&](const ushort* csrc, int M, ushort* csdst) {
    if (mtg != 0) return;
    const int ar = (M == 16) ? n16 : ((M == 4) ? (n16 & 3) : 0);  // row clamp
    f32x4 acc[2];
    acc[0] = (f32x4){0.f,0.f,0.f,0.f}; acc[1] = (f32x4){0.f,0.f,0.f,0.f};
    #pragma unroll
    for (int kb = 0; kb < 4; kb++) {
      short8 a  = afrag(ar, kb);
      short8 c2 = *(const short8*)(csrc + ar*STR + kb*32 + kof);
      acc[0] = MFMA(a,  Bc[0][kb], acc[0]); acc[1] = MFMA(a,  Bc[1][kb], acc[1]);
      acc[0] = MFMA(c2, Bs[0][kb], acc[0]); acc[1] = MFMA(c2, Bs[1][kb], acc[1]);
    }
    #pragma unroll
    for (int j = 0; j < 2; j++) {
      const float bb = bcv[j] + bsv[j];
      f32x4 A = acc[j];
      const int c = ntg*32 + j*16 + n16;
      if (M == 16) {
        float h0=A[0]+bb, h1=A[1]+bb, h2=A[2]+bb, h3=A[3]+bb;
        pm[j] = fmaxf(pm[j], fmaxf(fmaxf(h0,h1), fmaxf(h2,h3)));
        csdst[quad*STR + c] = f2bf(A[0]+A[1]+A[2]+A[3] + 4.f*bb);
      } else if (M == 4) {
        if (quad == 0) {
          float h0=A[0]+bb, h1=A[1]+bb, h2=A[2]+bb, h3=A[3]+bb;
          pm[j] = fmaxf(pm[j], fmaxf(fmaxf(h0,h1), fmaxf(h2,h3)));
          csdst[c] = f2bf(A[0]+A[1]+A[2]+A[3] + 4.f*bb);   // H1 = sum of 4 h1
        }
      } else {
        if (quad == 0) pm[j] = fmaxf(pm[j], A[0] + bb);    // root h0
      }
    }
  };

  // ---- 24-phase driver: [sync: prev Xf readers done] dma [sync: drain] compute
  __syncthreads();                             // PM/CS init visible
  for (int q = 0; q < 4; q++) {
    for (int g = 0; g < 4; g++) {              // leaves (q,g) -> CS4 rows g*16
      dma64(341 + q*256 + g*64);
      __syncthreads();
      phase64(nullptr, CS4, g*16);
      __syncthreads();
    }
    dma64(85 + q*64);                          // L4 quarter q (dual) -> CS3
    __syncthreads();
    phase64(CS4, CS3, q*16);
    __syncthreads();
  }
  dma64(21);                                   // L3 (64 nodes, dual) -> CS2
  __syncthreads();
  phase64(CS3, CS2, 0);
  __syncthreads();
  dmaS(5);                                     // L2 (16 nodes) -> CS1
  __syncthreads();
  smallphase(CS2, 16, CS1);
  __syncthreads();
  dmaS(1);                                     // L1 (4 nodes) -> H1 (CS2 row 0)
  __syncthreads();
  smallphase(CS1, 4, CS2);
  __syncthreads();
  dmaS(0);                                     // root
  __syncthreads();
  smallphase(CS2, 1, nullptr);

  // ---- merge per-lane maxima -> PM -> out ----
  #pragma unroll
  for (int j = 0; j < 2; j++) {
    float v = pm[j];
    v = fmaxf(v, __shfl_xor(v, 16, 64));
    v = fmaxf(v, __shfl_xor(v, 32, 64));
    if (quad == 0) PM[w*128 + ntg*32 + j*16 + n16] = v;
  }
  __syncthreads();
  if (tid < 128) {
    float m = 0.f;
    #pragma unroll
    for (int r = 0; r < 8; r++) m = fmaxf(m, PM[r*128 + tid]);
    out[(long)b*ED + tid] = m;
  }
}

extern "C" void kernel_launch(void* const* d_in, const int* in_sizes, int n_in,
                              void* d_out, int out_size, void* d_ws, size_t ws_size,
                              hipStream_t stream) {
  const int*   tokens = (const int*)d_in[0];
  const float* emb    = (const float*)d_in[1];
  const float* WcW    = (const float*)d_in[2];
  const float* Wcb    = (const float*)d_in[3];
  const float* WsW    = (const float*)d_in[4];
  const float* Wsb    = (const float*)d_in[5];
  float* out = (float*)d_out;
  (void)d_ws; (void)ws_size;

  hipFuncSetAttribute(reinterpret_cast<const void*>(tree_kernel),
                      hipFuncAttributeMaxDynamicSharedMemorySize, SM_BYTES);
  tree_kernel<<<512, 512, SM_BYTES, stream>>>(tokens, emb, WcW, Wcb, WsW, Wsb, out);
}